// Round 1
// 791.218 us; speedup vs baseline: 1.0307x; 1.0307x over previous
//
#include <hip/hip_runtime.h>

// VQ: B=200000 rows (D=128 fp32) vs K=1024 codes; out = [quant B*D | codes B] fp32.
//
// R3: kernel is VALU-issue-bound; v_pk_fma_f32 runs at the fp32 FLOP rate
// (~4cyc/wave-inst -> 333us MAC floor). Changes vs R2-best:
//  (1) 8x8 register tile (BM=64, BN=256, DCH=16): 4 ds_read_b128 feed 32
//      pk_fma per d (was 3:16) -> LDS instr pressure per MAC halved.
//  (2) inline-asm v_pk_fma_f32 with op_sel broadcast of the x operand ->
//      zero splat movs; inner loop is pure pk_fma + loads.
//  (3) shfl_xor argmin reduction (rows map to consecutive 32-lane groups) ->
//      no 32-way-conflicted LDS reduction array.
// Numerics: every (row,code) distance keeps the exact serial-over-d fma chain,
// same xsq 4-chain formula, same csq kernel, same tie-breaks -> decisions
// bit-identical to the passing R2 kernel.

typedef float v2f __attribute__((ext_vector_type(2)));

#define DDIM 128
#define KCODES 1024
#define BM 64              // rows per block (200000 = 3125 * 64, exact)
#define BN 256             // codes per tile
#define DCH 16             // d-chunk
#define NTILES (KCODES / BN)   // 4
#define NCHUNK (DDIM / DCH)    // 8

__global__ void csq_kernel(const float* __restrict__ cb, float* __restrict__ csq) {
    int k = blockIdx.x * blockDim.x + threadIdx.x;
    if (k >= KCODES) return;
    const float* __restrict__ c = cb + (long)k * DDIM;
    float s0 = 0.f, s1 = 0.f, s2 = 0.f, s3 = 0.f;
#pragma unroll
    for (int d = 0; d < DDIM; d += 4) {
        s0 = fmaf(c[d + 0], c[d + 0], s0);
        s1 = fmaf(c[d + 1], c[d + 1], s1);
        s2 = fmaf(c[d + 2], c[d + 2], s2);
        s3 = fmaf(c[d + 3], c[d + 3], s3);
    }
    csq[k] = (s0 + s1) + (s2 + s3);
}

// Packed fp32 fma, src0 (x) broadcast via op_sel -- no splat movs.
// PK_LO: both result halves use src0.lo; PK_HI: both use src0.hi.
#define PK_LO(a, xx, cc) \
    asm("v_pk_fma_f32 %0, %1, %2, %0 op_sel:[0,0,0] op_sel_hi:[0,1,1]" \
        : "+v"(a) : "v"(xx), "v"(cc))
#define PK_HI(a, xx, cc) \
    asm("v_pk_fma_f32 %0, %1, %2, %0 op_sel:[1,0,0] op_sel_hi:[1,1,1]" \
        : "+v"(a) : "v"(xx), "v"(cc))

__launch_bounds__(256, 3)  // LDS ~48.3KB -> 3 blocks/CU (12 waves/CU)
__global__ void vq_gemm_kernel(const float* __restrict__ x, const float* __restrict__ cb,
                               const float* __restrict__ csq, float* __restrict__ quant,
                               float* __restrict__ codes) {
    __shared__ float xs[DDIM * BM];   // [d][r] transposed, 32 KB, staged once
    __shared__ float cs[DCH * BN];    // [d][k] transposed, 16 KB
    __shared__ int win[BM];

    const int tid = threadIdx.x;
    const long r0 = (long)blockIdx.x * BM;

    // ---- stage x tile (64 rows x 128 d), transposed into xs[d][r] ----
    {
        const int r = tid >> 2;            // 0..63
        const int qb = (tid & 3) * 8;
        const float* __restrict__ xrow = x + (r0 + r) * DDIM;
#pragma unroll
        for (int j = 0; j < 8; ++j) {
            const int q = qb + j;          // quad 0..31, d = q*4
            const float4 v = *(const float4*)(xrow + q * 4);
            xs[(q * 4 + 0) * BM + r] = v.x;
            xs[(q * 4 + 1) * BM + r] = v.y;
            xs[(q * 4 + 2) * BM + r] = v.z;
            xs[(q * 4 + 3) * BM + r] = v.w;
        }
    }
    __syncthreads();

    const int tr = tid >> 5;   // 0..7  -> rows tr*8..+7
    const int tc = tid & 31;   // 0..31 -> codes {tc*4..+3} u {128+tc*4..+3} per tile

    // ---- x_sq per row: 4 chains (d mod 4), same association as R2 ----
    float s[4][8];
#pragma unroll
    for (int a = 0; a < 4; ++a)
#pragma unroll
        for (int b = 0; b < 8; ++b) s[a][b] = 0.f;
#pragma unroll
    for (int d = 0; d < DDIM; d += 4) {
#pragma unroll
        for (int dd = 0; dd < 4; ++dd) {
            const float4 a0 = *(const float4*)&xs[(d + dd) * BM + tr * 8];
            const float4 a1 = *(const float4*)&xs[(d + dd) * BM + tr * 8 + 4];
            s[dd][0] = fmaf(a0.x, a0.x, s[dd][0]);
            s[dd][1] = fmaf(a0.y, a0.y, s[dd][1]);
            s[dd][2] = fmaf(a0.z, a0.z, s[dd][2]);
            s[dd][3] = fmaf(a0.w, a0.w, s[dd][3]);
            s[dd][4] = fmaf(a1.x, a1.x, s[dd][4]);
            s[dd][5] = fmaf(a1.y, a1.y, s[dd][5]);
            s[dd][6] = fmaf(a1.z, a1.z, s[dd][6]);
            s[dd][7] = fmaf(a1.w, a1.w, s[dd][7]);
        }
    }
    float xsq[8];
#pragma unroll
    for (int i = 0; i < 8; ++i) xsq[i] = (s[0][i] + s[1][i]) + (s[2][i] + s[3][i]);

    float best[8];
    int bidx[8];
#pragma unroll
    for (int i = 0; i < 8; ++i) { best[i] = 3.4e38f; bidx[i] = 0; }

#pragma unroll 1
    for (int ct = 0; ct < NTILES; ++ct) {
        v2f acc[8][4];   // [row i][code-pair jj]; jj<2 -> codes tc*4+{2jj,2jj+1}, jj>=2 -> 128+...
#pragma unroll
        for (int i = 0; i < 8; ++i)
#pragma unroll
            for (int jj = 0; jj < 4; ++jj) acc[i][jj] = (v2f){0.f, 0.f};

#pragma unroll 1
        for (int dc = 0; dc < NCHUNK; ++dc) {
            __syncthreads();  // protect cs from previous chunk readers
            {   // stage codebook chunk: code k = ct*BN+tid, dims dc*16..+15
                const float* __restrict__ crow =
                    cb + (long)(ct * BN + tid) * DDIM + dc * DCH;
#pragma unroll
                for (int j = 0; j < 4; ++j) {
                    const float4 v = *(const float4*)(crow + j * 4);
                    cs[(j * 4 + 0) * BN + tid] = v.x;
                    cs[(j * 4 + 1) * BN + tid] = v.y;
                    cs[(j * 4 + 2) * BN + tid] = v.z;
                    cs[(j * 4 + 3) * BN + tid] = v.w;
                }
            }
            __syncthreads();
#pragma unroll
            for (int d = 0; d < DCH; ++d) {
                // x reads: 2 addresses/wave (broadcast). c reads: stride-16B
                // across 32 lanes -> full bank coverage, conflict-free.
                const float4 xa0 = *(const float4*)&xs[(dc * DCH + d) * BM + tr * 8];
                const float4 xa1 = *(const float4*)&xs[(dc * DCH + d) * BM + tr * 8 + 4];
                const float4 ca0 = *(const float4*)&cs[d * BN + tc * 4];
                const float4 ca1 = *(const float4*)&cs[d * BN + 128 + tc * 4];
                v2f xp[4], cp[4];
                xp[0] = (v2f){xa0.x, xa0.y}; xp[1] = (v2f){xa0.z, xa0.w};
                xp[2] = (v2f){xa1.x, xa1.y}; xp[3] = (v2f){xa1.z, xa1.w};
                cp[0] = (v2f){ca0.x, ca0.y}; cp[1] = (v2f){ca0.z, ca0.w};
                cp[2] = (v2f){ca1.x, ca1.y}; cp[3] = (v2f){ca1.z, ca1.w};
#pragma unroll
                for (int jj = 0; jj < 4; ++jj) {
                    PK_LO(acc[0][jj], xp[0], cp[jj]);
                    PK_HI(acc[1][jj], xp[0], cp[jj]);
                    PK_LO(acc[2][jj], xp[1], cp[jj]);
                    PK_HI(acc[3][jj], xp[1], cp[jj]);
                    PK_LO(acc[4][jj], xp[2], cp[jj]);
                    PK_HI(acc[5][jj], xp[2], cp[jj]);
                    PK_LO(acc[6][jj], xp[3], cp[jj]);
                    PK_HI(acc[7][jj], xp[3], cp[jj]);
                }
            }
        }

        // ---- tile epilogue: dist + running argmin (ascending code order) ----
        float csq_r[8];
#pragma unroll
        for (int j = 0; j < 4; ++j) {
            csq_r[j]     = csq[ct * BN + tc * 4 + j];
            csq_r[4 + j] = csq[ct * BN + 128 + tc * 4 + j];
        }
#pragma unroll
        for (int i = 0; i < 8; ++i) {
#pragma unroll
            for (int jj = 0; jj < 4; ++jj) {
#pragma unroll
                for (int h = 0; h < 2; ++h) {
                    const int jl = jj * 2 + h;  // 0..7, ascending
                    const int cj = ct * BN + ((jl < 4) ? (tc * 4 + jl) : (128 + tc * 4 + jl - 4));
                    const float dist = fmaf(-2.0f, acc[i][jj][h], xsq[i]) + csq_r[jl];
                    if (dist < best[i]) { best[i] = dist; bidx[i] = cj; }
                }
            }
        }
    }

    // ---- cross-lane per-row argmin: rows of group tr live in 32 consecutive
    // lanes (tid = tr*32 + tc) -> xor-butterfly within the 32-lane half ----
#pragma unroll
    for (int i = 0; i < 8; ++i) {
#pragma unroll
        for (int off = 16; off >= 1; off >>= 1) {
            const float ov = __shfl_xor(best[i], off);
            const int ovi = __shfl_xor(bidx[i], off);
            if (ov < best[i] || (ov == best[i] && ovi < bidx[i])) {
                best[i] = ov; bidx[i] = ovi;
            }
        }
    }
    if (tc == 0) {
#pragma unroll
        for (int i = 0; i < 8; ++i) {
            const int r = tr * 8 + i;
            codes[r0 + r] = (float)bidx[i];
            win[r] = bidx[i];
        }
    }
    __syncthreads();

    // ---- gather winner rows ----
    {
        const int r = tid >> 2;
        const int qb = (tid & 3) * 8;
        const float* __restrict__ crow = cb + (long)win[r] * DDIM;
        float* __restrict__ qrow = quant + (r0 + r) * DDIM;
#pragma unroll
        for (int j = 0; j < 8; ++j) {
            const int q = qb + j;
            *(float4*)(qrow + q * 4) = *(const float4*)(crow + q * 4);
        }
    }
}

extern "C" void kernel_launch(void* const* d_in, const int* in_sizes, int n_in,
                              void* d_out, int out_size, void* d_ws, size_t ws_size,
                              hipStream_t stream) {
    const float* x  = (const float*)d_in[0];
    const float* cb = (const float*)d_in[1];
    const int B = in_sizes[0] / DDIM;  // 200000

    float* quant = (float*)d_out;
    float* codes = (float*)d_out + (size_t)B * DDIM;
    float* csq   = (float*)d_ws;

    csq_kernel<<<(KCODES + 255) / 256, 256, 0, stream>>>(cb, csq);

    const int blocks = B / BM;  // 3125 exact
    vq_gemm_kernel<<<blocks, 256, 0, stream>>>(x, cb, csq, quant, codes);
}